// Round 3
// baseline (620.548 us; speedup 1.0000x reference)
//
#include <hip/hip_runtime.h>

#define N_NODES 150000
#define N_EDGES 2400000
#define F_IN    22
#define HID     32
#define N_CLS   6
#define BN_EPS  1e-5f

#define BSHIFT  8
#define NB      ((N_NODES + 255) >> 8)              // 586 buckets of 256 nodes
#define CHUNK   8192
#define EPT     (CHUNK / 256)                       // 32 edges per thread
#define NBLK_BIN ((N_EDGES + CHUNK - 1) / CHUNK)    // 293 blocks

// ---------------------------------------------------------------------------
// K0: per-node h = relu(x@W_emb + b_emb) @ W_gcn  (unscaled; dis applied later)
// ---------------------------------------------------------------------------
__global__ void embed_kernel(const float* __restrict__ x,
                             const float* __restrict__ W_emb,
                             const float* __restrict__ b_emb,
                             const float* __restrict__ W_gcn,
                             float* __restrict__ h) {
    __shared__ float sWe[F_IN * HID];
    __shared__ float sbe[HID];
    __shared__ float sWg[HID * HID];
    for (int t = threadIdx.x; t < F_IN * HID; t += blockDim.x) sWe[t] = W_emb[t];
    if (threadIdx.x < HID) sbe[threadIdx.x] = b_emb[threadIdx.x];
    for (int t = threadIdx.x; t < HID * HID; t += blockDim.x) sWg[t] = W_gcn[t];
    __syncthreads();

    int i = blockIdx.x * blockDim.x + threadIdx.x;
    if (i >= N_NODES) return;

    float xi[F_IN];
#pragma unroll
    for (int f = 0; f < F_IN; ++f) xi[f] = x[(size_t)i * F_IN + f];

    float h1[HID];
#pragma unroll
    for (int j = 0; j < HID; ++j) {
        float acc = sbe[j];
#pragma unroll
        for (int f = 0; f < F_IN; ++f) acc = fmaf(xi[f], sWe[f * HID + j], acc);
        h1[j] = fmaxf(acc, 0.0f);
    }
#pragma unroll
    for (int j = 0; j < HID; ++j) {
        float acc = 0.0f;
#pragma unroll
        for (int f = 0; f < HID; ++f) acc = fmaf(h1[f], sWg[f * HID + j], acc);
        h[(size_t)i * HID + j] = acc;
    }
}

// ---------------------------------------------------------------------------
// K1: coarse bucket histogram (bucket = dst>>8), LDS-privatized
// ---------------------------------------------------------------------------
__global__ void bucket_hist_kernel(const int* __restrict__ dst,
                                   int* __restrict__ bcnt) {
    __shared__ int hloc[NB];
    for (int t = threadIdx.x; t < NB; t += 256) hloc[t] = 0;
    __syncthreads();
    int base = blockIdx.x * CHUNK;
    int end = base + CHUNK; if (end > N_EDGES) end = N_EDGES;
    for (int i = base + threadIdx.x; i < end; i += 256)
        atomicAdd(&hloc[dst[i] >> BSHIFT], 1);
    __syncthreads();
    for (int t = threadIdx.x; t < NB; t += 256)
        if (hloc[t]) atomicAdd(&bcnt[t], hloc[t]);
}

// ---------------------------------------------------------------------------
// K2: single-block exclusive scan of NB bucket counts -> boff, bcur
// ---------------------------------------------------------------------------
__global__ void bucket_scan_kernel(const int* __restrict__ bcnt,
                                   int* __restrict__ boff,
                                   int* __restrict__ bcur) {
    __shared__ int s[1024];
    int t = threadIdx.x;
    int v0 = (t < NB) ? bcnt[t] : 0;
    s[t] = v0;
    __syncthreads();
#pragma unroll
    for (int o = 1; o < 1024; o <<= 1) {
        int v = (t >= o) ? s[t - o] : 0;
        __syncthreads();
        s[t] += v;                 // inclusive
        __syncthreads();
    }
    if (t < NB) {
        int e = s[t] - v0;         // exclusive
        boff[t] = e;
        bcur[t] = e;
    }
    if (t == NB - 1) boff[NB] = s[t];   // == N_EDGES
}

// ---------------------------------------------------------------------------
// K3: binned append. Per block: LDS hist of its chunk -> one global atomic per
//     bucket to reserve a range -> sequential-run writes of packed entries.
//     packed = (dst & 255) << 24 | src   (src < 2^24)
// ---------------------------------------------------------------------------
__global__ void bin_edges_kernel(const int* __restrict__ src,
                                 const int* __restrict__ dst,
                                 int* __restrict__ bcur,
                                 unsigned int* __restrict__ binned) {
    __shared__ int hloc[NB];
    __shared__ int base[NB];
    __shared__ int lcur[NB];
    for (int t = threadIdx.x; t < NB; t += 256) hloc[t] = 0;
    __syncthreads();

    int cbase = blockIdx.x * CHUNK;
    int dreg[EPT];
#pragma unroll
    for (int k = 0; k < EPT; ++k) {
        int i = cbase + threadIdx.x + k * 256;
        int d = -1;
        if (i < N_EDGES) {
            d = dst[i];
            atomicAdd(&hloc[d >> BSHIFT], 1);
        }
        dreg[k] = d;
    }
    __syncthreads();
    for (int t = threadIdx.x; t < NB; t += 256) {
        int c = hloc[t];
        base[t] = c ? atomicAdd(&bcur[t], c) : 0;
        lcur[t] = 0;
    }
    __syncthreads();
#pragma unroll
    for (int k = 0; k < EPT; ++k) {
        int d = dreg[k];
        if (d < 0) continue;
        int i = cbase + threadIdx.x + k * 256;
        int b = d >> BSHIFT;
        int r = atomicAdd(&lcur[b], 1);
        binned[base[b] + r] = ((unsigned)(d & 255) << 24) | (unsigned)src[i];
    }
}

// ---------------------------------------------------------------------------
// K4: per-bucket node degrees from binned data (no global atomics!),
//     dis = rsqrt(1+deg), scale h rows in place: hs = h * dis
// ---------------------------------------------------------------------------
__global__ void degree_scale_kernel(const int* __restrict__ boff,
                                    const unsigned int* __restrict__ binned,
                                    float* __restrict__ h,
                                    float* __restrict__ dis) {
    __shared__ int cnt[256];
    __shared__ float dl[256];
    int b = blockIdx.x;
    cnt[threadIdx.x] = 0;
    __syncthreads();
    int s0 = boff[b], s1 = boff[b + 1];
    for (int k = s0 + threadIdx.x; k < s1; k += 256)
        atomicAdd(&cnt[binned[k] >> 24], 1);
    __syncthreads();
    int nbase = b << BSHIFT;
    int nnode = N_NODES - nbase; if (nnode > 256) nnode = 256;
    if (threadIdx.x < nnode) {
        float d = rsqrtf(1.0f + (float)cnt[threadIdx.x]);
        dl[threadIdx.x] = d;
        dis[nbase + threadIdx.x] = d;
    }
    __syncthreads();
    float4* hv = reinterpret_cast<float4*>(h) + (size_t)nbase * 8;
    for (int t = threadIdx.x; t < nnode * 8; t += 256) {
        float4 v = hv[t];
        float d = dl[t >> 3];
        v.x *= d; v.y *= d; v.z *= d; v.w *= d;
        hv[t] = v;
    }
}

// ---------------------------------------------------------------------------
// K5: per-bucket aggregation into padded LDS tile + fused BN-stats partials.
//     agg[n] = (sum_{in-edges} hs[src] + hs[n]) * dis[n]
// ---------------------------------------------------------------------------
__global__ void aggregate_kernel(const int* __restrict__ boff,
                                 const unsigned int* __restrict__ binned,
                                 const float* __restrict__ hs,
                                 const float* __restrict__ dis,
                                 float* __restrict__ agg,
                                 float* __restrict__ stats) {
    __shared__ float al[256 * 33];     // +1 pad breaks 32-bank collision
    __shared__ float dl[256];
    int b = blockIdx.x;
    int nbase = b << BSHIFT;
    int nnode = N_NODES - nbase; if (nnode > 256) nnode = 256;

    for (int t = threadIdx.x; t < 256 * 33; t += 256) al[t] = 0.0f;
    if (threadIdx.x < nnode) dl[threadIdx.x] = dis[nbase + threadIdx.x];
    __syncthreads();

    int s0 = boff[b], s1 = boff[b + 1];
    for (int k = s0 + threadIdx.x; k < s1; k += 256) {
        unsigned p = binned[k];
        int n = (int)(p >> 24);
        int s = (int)(p & 0xFFFFFFu);
        const float4* row = reinterpret_cast<const float4*>(hs) + (size_t)s * 8;
        float* a = &al[n * 33];
#pragma unroll
        for (int c = 0; c < 8; ++c) {
            float4 v = row[c];
            atomicAdd(a + c * 4 + 0, v.x);
            atomicAdd(a + c * 4 + 1, v.y);
            atomicAdd(a + c * 4 + 2, v.z);
            atomicAdd(a + c * 4 + 3, v.w);
        }
    }
    __syncthreads();

    // write-out + per-thread BN partials (thread's c = tid&7 is constant)
    float4 ps = {0.f, 0.f, 0.f, 0.f};
    float4 pq = {0.f, 0.f, 0.f, 0.f};
    const float4* hv = reinterpret_cast<const float4*>(hs) + (size_t)nbase * 8;
    float4* av = reinterpret_cast<float4*>(agg) + (size_t)nbase * 8;
    for (int t = threadIdx.x; t < nnode * 8; t += 256) {
        int n = t >> 3, c = t & 7;
        float4 v = hv[t];                    // self-loop term (already *dis[n])
        float d = dl[n];
        const float* a = &al[n * 33 + c * 4];
        float4 o;
        o.x = (a[0] + v.x) * d;
        o.y = (a[1] + v.y) * d;
        o.z = (a[2] + v.z) * d;
        o.w = (a[3] + v.w) * d;
        av[t] = o;
        ps.x += o.x; ps.y += o.y; ps.z += o.z; ps.w += o.w;
        pq.x = fmaf(o.x, o.x, pq.x); pq.y = fmaf(o.y, o.y, pq.y);
        pq.z = fmaf(o.z, o.z, pq.z); pq.w = fmaf(o.w, o.w, pq.w);
    }
    __syncthreads();                         // al no longer needed -> reuse
    float* S = al;                           // [256][4] sums
    float* Q = al + 1024;                    // [256][4] sumsq
    S[threadIdx.x * 4 + 0] = ps.x; S[threadIdx.x * 4 + 1] = ps.y;
    S[threadIdx.x * 4 + 2] = ps.z; S[threadIdx.x * 4 + 3] = ps.w;
    Q[threadIdx.x * 4 + 0] = pq.x; Q[threadIdx.x * 4 + 1] = pq.y;
    Q[threadIdx.x * 4 + 2] = pq.z; Q[threadIdx.x * 4 + 3] = pq.w;
    __syncthreads();
    if (threadIdx.x < 32) {
        int c = threadIdx.x >> 2, j = threadIdx.x & 3;
        float s = 0.0f, q = 0.0f;
#pragma unroll
        for (int w = 0; w < 32; ++w) {       // threads with tid&7 == c
            int tid = (w << 3) | c;
            s += S[tid * 4 + j];
            q += Q[tid * 4 + j];
        }
        atomicAdd(&stats[threadIdx.x], s);
        atomicAdd(&stats[32 + threadIdx.x], q);
    }
}

// ---------------------------------------------------------------------------
// K6: fold BN into affine A,B:  hn = agg*A + B
// ---------------------------------------------------------------------------
__global__ void finalize_stats_kernel(const float* __restrict__ stats,
                                      const float* __restrict__ gamma,
                                      const float* __restrict__ beta,
                                      float* __restrict__ AB) {
    int f = threadIdx.x;
    if (f < HID) {
        const float invN = 1.0f / (float)N_NODES;
        float mean = stats[f] * invN;
        float var = stats[32 + f] * invN - mean * mean;
        float inv = rsqrtf(var + BN_EPS);
        float A = gamma[f] * inv;
        AB[f] = A;
        AB[32 + f] = beta[f] - mean * A;
    }
}

// ---------------------------------------------------------------------------
// K7: out = relu(agg*A + B) @ W_cls + b_cls
// ---------------------------------------------------------------------------
__global__ void cls_kernel(const float* __restrict__ agg,
                           const float* __restrict__ AB,
                           const float* __restrict__ W_cls,
                           const float* __restrict__ b_cls,
                           float* __restrict__ out) {
    __shared__ float sA[HID];
    __shared__ float sB[HID];
    __shared__ float sW[HID * N_CLS];
    __shared__ float sb[N_CLS];
    if (threadIdx.x < HID) {
        sA[threadIdx.x] = AB[threadIdx.x];
        sB[threadIdx.x] = AB[32 + threadIdx.x];
    }
    for (int t = threadIdx.x; t < HID * N_CLS; t += blockDim.x) sW[t] = W_cls[t];
    if (threadIdx.x < N_CLS) sb[threadIdx.x] = b_cls[threadIdx.x];
    __syncthreads();

    int i = blockIdx.x * blockDim.x + threadIdx.x;
    if (i >= N_NODES) return;

    float acc[N_CLS];
#pragma unroll
    for (int c = 0; c < N_CLS; ++c) acc[c] = sb[c];
#pragma unroll
    for (int f = 0; f < HID; ++f) {
        float t = fmaxf(fmaf(agg[(size_t)i * HID + f], sA[f], sB[f]), 0.0f);
#pragma unroll
        for (int c = 0; c < N_CLS; ++c) acc[c] = fmaf(t, sW[f * N_CLS + c], acc[c]);
    }
#pragma unroll
    for (int c = 0; c < N_CLS; ++c) out[(size_t)i * N_CLS + c] = acc[c];
}

// ---------------------------------------------------------------------------
extern "C" void kernel_launch(void* const* d_in, const int* in_sizes, int n_in,
                              void* d_out, int out_size, void* d_ws, size_t ws_size,
                              hipStream_t stream) {
    const float* x     = (const float*)d_in[0];
    const int*   edge  = (const int*)d_in[1];   // [2, E] int32
    const float* W_emb = (const float*)d_in[2];
    const float* b_emb = (const float*)d_in[3];
    const float* W_gcn = (const float*)d_in[4];
    // d_in[5] = b_gcn: per-feature constant, cancels exactly in BatchNorm -> skip
    const float* gamma = (const float*)d_in[6];
    const float* beta  = (const float*)d_in[7];
    const float* W_cls = (const float*)d_in[8];
    const float* b_cls = (const float*)d_in[9];
    float* out = (float*)d_out;

    // workspace layout (~49 MB)
    float*        h      = (float*)d_ws;                      // N*HID (scaled in place)
    float*        agg    = h + (size_t)N_NODES * HID;         // N*HID
    float*        dis    = agg + (size_t)N_NODES * HID;       // N
    int*          bcnt   = (int*)(dis + N_NODES);             // NB
    int*          boff   = bcnt + NB;                         // NB+1
    int*          bcur   = boff + NB + 1;                     // NB
    unsigned int* binned = (unsigned int*)(bcur + NB);        // E
    float*        stats  = (float*)(binned + N_EDGES);        // 64
    float*        AB     = stats + 64;                        // 64

    hipMemsetAsync(bcnt, 0, NB * sizeof(int), stream);
    hipMemsetAsync(stats, 0, 64 * sizeof(float), stream);

    const int* src = edge;
    const int* dst = edge + N_EDGES;

    embed_kernel<<<(N_NODES + 255) / 256, 256, 0, stream>>>(x, W_emb, b_emb, W_gcn, h);
    bucket_hist_kernel<<<NBLK_BIN, 256, 0, stream>>>(dst, bcnt);
    bucket_scan_kernel<<<1, 1024, 0, stream>>>(bcnt, boff, bcur);
    bin_edges_kernel<<<NBLK_BIN, 256, 0, stream>>>(src, dst, bcur, binned);
    degree_scale_kernel<<<NB, 256, 0, stream>>>(boff, binned, h, dis);
    aggregate_kernel<<<NB, 256, 0, stream>>>(boff, binned, h, dis, agg, stats);
    finalize_stats_kernel<<<1, 64, 0, stream>>>(stats, gamma, beta, AB);
    cls_kernel<<<(N_NODES + 255) / 256, 256, 0, stream>>>(agg, AB, W_cls, b_cls, out);
}

// Round 4
// 209.097 us; speedup vs baseline: 2.9678x; 2.9678x over previous
//
#include <hip/hip_runtime.h>

#define N_NODES 150000
#define N_EDGES 2400000
#define F_IN    22
#define HID     32
#define N_CLS   6
#define BN_EPS  1e-5f

#define BSHIFT  8
#define NB      ((N_NODES + 255) >> 8)              // 586 buckets of 256 nodes
#define CHUNK   8192
#define EPT     (CHUNK / 256)                       // 32 edges per thread
#define NBLK_BIN ((N_EDGES + CHUNK - 1) / CHUNK)    // 293 blocks

// ---------------------------------------------------------------------------
// K0: per-node h = relu(x@W_emb + b_emb) @ W_gcn  (unscaled; dis applied later)
// ---------------------------------------------------------------------------
__global__ void embed_kernel(const float* __restrict__ x,
                             const float* __restrict__ W_emb,
                             const float* __restrict__ b_emb,
                             const float* __restrict__ W_gcn,
                             float* __restrict__ h) {
    __shared__ float sWe[F_IN * HID];
    __shared__ float sbe[HID];
    __shared__ float sWg[HID * HID];
    for (int t = threadIdx.x; t < F_IN * HID; t += blockDim.x) sWe[t] = W_emb[t];
    if (threadIdx.x < HID) sbe[threadIdx.x] = b_emb[threadIdx.x];
    for (int t = threadIdx.x; t < HID * HID; t += blockDim.x) sWg[t] = W_gcn[t];
    __syncthreads();

    int i = blockIdx.x * blockDim.x + threadIdx.x;
    if (i >= N_NODES) return;

    float xi[F_IN];
#pragma unroll
    for (int f = 0; f < F_IN; ++f) xi[f] = x[(size_t)i * F_IN + f];

    float h1[HID];
#pragma unroll
    for (int j = 0; j < HID; ++j) {
        float acc = sbe[j];
#pragma unroll
        for (int f = 0; f < F_IN; ++f) acc = fmaf(xi[f], sWe[f * HID + j], acc);
        h1[j] = fmaxf(acc, 0.0f);
    }
#pragma unroll
    for (int j = 0; j < HID; ++j) {
        float acc = 0.0f;
#pragma unroll
        for (int f = 0; f < HID; ++f) acc = fmaf(h1[f], sWg[f * HID + j], acc);
        h[(size_t)i * HID + j] = acc;
    }
}

// ---------------------------------------------------------------------------
// K1: coarse bucket histogram (bucket = dst>>8), LDS-privatized
// ---------------------------------------------------------------------------
__global__ void bucket_hist_kernel(const int* __restrict__ dst,
                                   int* __restrict__ bcnt) {
    __shared__ int hloc[NB];
    for (int t = threadIdx.x; t < NB; t += 256) hloc[t] = 0;
    __syncthreads();
    int base = blockIdx.x * CHUNK;
    int end = base + CHUNK; if (end > N_EDGES) end = N_EDGES;
    for (int i = base + threadIdx.x; i < end; i += 256)
        atomicAdd(&hloc[dst[i] >> BSHIFT], 1);
    __syncthreads();
    for (int t = threadIdx.x; t < NB; t += 256)
        if (hloc[t]) atomicAdd(&bcnt[t], hloc[t]);
}

// ---------------------------------------------------------------------------
// K2: single-block exclusive scan of NB bucket counts -> boff, bcur
// ---------------------------------------------------------------------------
__global__ void bucket_scan_kernel(const int* __restrict__ bcnt,
                                   int* __restrict__ boff,
                                   int* __restrict__ bcur) {
    __shared__ int s[1024];
    int t = threadIdx.x;
    int v0 = (t < NB) ? bcnt[t] : 0;
    s[t] = v0;
    __syncthreads();
#pragma unroll
    for (int o = 1; o < 1024; o <<= 1) {
        int v = (t >= o) ? s[t - o] : 0;
        __syncthreads();
        s[t] += v;                 // inclusive
        __syncthreads();
    }
    if (t < NB) {
        int e = s[t] - v0;         // exclusive
        boff[t] = e;
        bcur[t] = e;
    }
    if (t == NB - 1) boff[NB] = s[t];   // == N_EDGES
}

// ---------------------------------------------------------------------------
// K3: binned append. Per block: LDS hist of its chunk -> one global atomic per
//     bucket to reserve a range -> sequential-run writes of packed entries.
//     packed = (dst & 255) << 24 | src   (src < 2^24)
// ---------------------------------------------------------------------------
__global__ void bin_edges_kernel(const int* __restrict__ src,
                                 const int* __restrict__ dst,
                                 int* __restrict__ bcur,
                                 unsigned int* __restrict__ binned) {
    __shared__ int hloc[NB];
    __shared__ int base[NB];
    __shared__ int lcur[NB];
    for (int t = threadIdx.x; t < NB; t += 256) hloc[t] = 0;
    __syncthreads();

    int cbase = blockIdx.x * CHUNK;
    int dreg[EPT];
#pragma unroll
    for (int k = 0; k < EPT; ++k) {
        int i = cbase + threadIdx.x + k * 256;
        int d = -1;
        if (i < N_EDGES) {
            d = dst[i];
            atomicAdd(&hloc[d >> BSHIFT], 1);
        }
        dreg[k] = d;
    }
    __syncthreads();
    for (int t = threadIdx.x; t < NB; t += 256) {
        int c = hloc[t];
        base[t] = c ? atomicAdd(&bcur[t], c) : 0;
        lcur[t] = 0;
    }
    __syncthreads();
#pragma unroll
    for (int k = 0; k < EPT; ++k) {
        int d = dreg[k];
        if (d < 0) continue;
        int i = cbase + threadIdx.x + k * 256;
        int b = d >> BSHIFT;
        int r = atomicAdd(&lcur[b], 1);
        binned[base[b] + r] = ((unsigned)(d & 255) << 24) | (unsigned)src[i];
    }
}

// ---------------------------------------------------------------------------
// K4: per-bucket local counting sort -> fully dst-sorted sorted_src + off[],
//     plus dis = rsqrt(1+deg) and in-place h *= dis.
//     All heavy writes stay within this bucket's 16 KB window (L2-resident).
// ---------------------------------------------------------------------------
__global__ void bucket_csr_kernel(const int* __restrict__ boff,
                                  unsigned int* __restrict__ binned,
                                  int* __restrict__ sorted_src,
                                  int* __restrict__ off,
                                  float* __restrict__ h,
                                  float* __restrict__ dis) {
    __shared__ int s_cnt[256];
    __shared__ int s_scan[256];
    __shared__ int s_cur[256];
    __shared__ float dl[256];
    int b = blockIdx.x;
    int t = threadIdx.x;
    int s0 = boff[b], s1 = boff[b + 1];
    int nbase = b << BSHIFT;
    int nnode = N_NODES - nbase; if (nnode > 256) nnode = 256;

    s_cnt[t] = 0;
    __syncthreads();
    for (int k = s0 + t; k < s1; k += 256)
        atomicAdd(&s_cnt[binned[k] >> 24], 1);
    __syncthreads();

    int v = s_cnt[t];
    s_scan[t] = v;
    __syncthreads();
#pragma unroll
    for (int o = 1; o < 256; o <<= 1) {
        int u = (t >= o) ? s_scan[t - o] : 0;
        __syncthreads();
        s_scan[t] += u;            // inclusive
        __syncthreads();
    }
    int excl = s_scan[t] - v;
    s_cur[t] = excl;
    if (t < nnode) {
        off[nbase + t] = s0 + excl;
        float d = rsqrtf(1.0f + (float)v);
        dl[t] = d;
        dis[nbase + t] = d;
    }
    if (b == NB - 1 && t == 0) off[N_NODES] = N_EDGES;
    __syncthreads();

    // scale this bucket's h rows in place: hs = h * dis
    float4* hv = reinterpret_cast<float4*>(h) + (size_t)nbase * 8;
    for (int tt = t; tt < nnode * 8; tt += 256) {
        float4 w = hv[tt];
        float d = dl[tt >> 3];
        w.x *= d; w.y *= d; w.z *= d; w.w *= d;
        hv[tt] = w;
    }

    // scatter to node-sorted order (writes stay inside [s0,s1) = 16 KB window)
    for (int k = s0 + t; k < s1; k += 256) {
        unsigned p = binned[k];
        int n = (int)(p >> 24);
        int r = atomicAdd(&s_cur[n], 1);
        sorted_src[s0 + r] = (int)(p & 0xFFFFFFu);
    }
}

// ---------------------------------------------------------------------------
// K5: per-node aggregation, 8 threads/node, coalesced float4 gathers, no
//     atomics.  agg[n] = (hs[n] + sum_{in(n)} hs[src]) * dis[n]
// ---------------------------------------------------------------------------
__global__ void aggregate_kernel(const int* __restrict__ off,
                                 const int* __restrict__ sorted_src,
                                 const float* __restrict__ hs,
                                 const float* __restrict__ dis,
                                 float* __restrict__ agg) {
    int t = blockIdx.x * blockDim.x + threadIdx.x;
    int node = t >> 3;
    int c = t & 7;
    if (node >= N_NODES) return;

    const float4* hrow = reinterpret_cast<const float4*>(hs);
    float4 acc = hrow[(size_t)node * 8 + c];          // self-loop term
    int b = off[node], e = off[node + 1];
    for (int k = b; k < e; ++k) {
        int s = sorted_src[k];
        float4 v = hrow[(size_t)s * 8 + c];
        acc.x += v.x; acc.y += v.y; acc.z += v.z; acc.w += v.w;
    }
    float d = dis[node];
    acc.x *= d; acc.y *= d; acc.z *= d; acc.w *= d;
    reinterpret_cast<float4*>(agg)[(size_t)node * 8 + c] = acc;
}

// ---------------------------------------------------------------------------
// K6: per-feature sum / sumsq over agg rows (stats[0..31]=sum, [32..63]=sumsq)
// ---------------------------------------------------------------------------
__global__ void stats_kernel(const float* __restrict__ agg,
                             float* __restrict__ stats) {
    float s = 0.0f, sq = 0.0f;
    int idx = blockIdx.x * blockDim.x + threadIdx.x;
    int stride = gridDim.x * blockDim.x;
    for (; idx < N_NODES * HID; idx += stride) {
        float v = agg[idx];
        s += v;
        sq = fmaf(v, v, sq);
    }
    __shared__ float ss[256];
    __shared__ float ssq[256];
    ss[threadIdx.x] = s;
    ssq[threadIdx.x] = sq;
    __syncthreads();
    if (threadIdx.x < 32) {
        float ts = 0.0f, tq = 0.0f;
#pragma unroll
        for (int g = 0; g < 256; g += 32) {
            ts += ss[g + threadIdx.x];
            tq += ssq[g + threadIdx.x];
        }
        atomicAdd(&stats[threadIdx.x], ts);
        atomicAdd(&stats[32 + threadIdx.x], tq);
    }
}

// ---------------------------------------------------------------------------
// K7: fold BN into affine A,B:  hn = agg*A + B
// ---------------------------------------------------------------------------
__global__ void finalize_stats_kernel(const float* __restrict__ stats,
                                      const float* __restrict__ gamma,
                                      const float* __restrict__ beta,
                                      float* __restrict__ AB) {
    int f = threadIdx.x;
    if (f < HID) {
        const float invN = 1.0f / (float)N_NODES;
        float mean = stats[f] * invN;
        float var = stats[32 + f] * invN - mean * mean;
        float inv = rsqrtf(var + BN_EPS);
        float A = gamma[f] * inv;
        AB[f] = A;
        AB[32 + f] = beta[f] - mean * A;
    }
}

// ---------------------------------------------------------------------------
// K8: out = relu(agg*A + B) @ W_cls + b_cls
// ---------------------------------------------------------------------------
__global__ void cls_kernel(const float* __restrict__ agg,
                           const float* __restrict__ AB,
                           const float* __restrict__ W_cls,
                           const float* __restrict__ b_cls,
                           float* __restrict__ out) {
    __shared__ float sA[HID];
    __shared__ float sB[HID];
    __shared__ float sW[HID * N_CLS];
    __shared__ float sb[N_CLS];
    if (threadIdx.x < HID) {
        sA[threadIdx.x] = AB[threadIdx.x];
        sB[threadIdx.x] = AB[32 + threadIdx.x];
    }
    for (int t = threadIdx.x; t < HID * N_CLS; t += blockDim.x) sW[t] = W_cls[t];
    if (threadIdx.x < N_CLS) sb[threadIdx.x] = b_cls[threadIdx.x];
    __syncthreads();

    int i = blockIdx.x * blockDim.x + threadIdx.x;
    if (i >= N_NODES) return;

    float acc[N_CLS];
#pragma unroll
    for (int c = 0; c < N_CLS; ++c) acc[c] = sb[c];
#pragma unroll
    for (int f = 0; f < HID; ++f) {
        float t = fmaxf(fmaf(agg[(size_t)i * HID + f], sA[f], sB[f]), 0.0f);
#pragma unroll
        for (int c = 0; c < N_CLS; ++c) acc[c] = fmaf(t, sW[f * N_CLS + c], acc[c]);
    }
#pragma unroll
    for (int c = 0; c < N_CLS; ++c) out[(size_t)i * N_CLS + c] = acc[c];
}

// ---------------------------------------------------------------------------
extern "C" void kernel_launch(void* const* d_in, const int* in_sizes, int n_in,
                              void* d_out, int out_size, void* d_ws, size_t ws_size,
                              hipStream_t stream) {
    const float* x     = (const float*)d_in[0];
    const int*   edge  = (const int*)d_in[1];   // [2, E] int32
    const float* W_emb = (const float*)d_in[2];
    const float* b_emb = (const float*)d_in[3];
    const float* W_gcn = (const float*)d_in[4];
    // d_in[5] = b_gcn: per-feature constant, cancels exactly in BatchNorm -> skip
    const float* gamma = (const float*)d_in[6];
    const float* beta  = (const float*)d_in[7];
    const float* W_cls = (const float*)d_in[8];
    const float* b_cls = (const float*)d_in[9];
    float* out = (float*)d_out;

    // workspace layout (~59 MB)
    float*        h          = (float*)d_ws;                    // N*HID (scaled in place)
    float*        agg        = h + (size_t)N_NODES * HID;       // N*HID
    float*        dis        = agg + (size_t)N_NODES * HID;     // N
    int*          off        = (int*)(dis + N_NODES);           // N+1
    int*          bcnt       = off + N_NODES + 1;               // NB
    int*          boff       = bcnt + NB;                       // NB+1
    int*          bcur       = boff + NB + 1;                   // NB
    unsigned int* binned     = (unsigned int*)(bcur + NB);      // E
    int*          sorted_src = (int*)(binned + N_EDGES);        // E
    float*        stats      = (float*)(sorted_src + N_EDGES);  // 64
    float*        AB         = stats + 64;                      // 64

    hipMemsetAsync(bcnt, 0, NB * sizeof(int), stream);
    hipMemsetAsync(stats, 0, 64 * sizeof(float), stream);

    const int* src = edge;
    const int* dst = edge + N_EDGES;

    embed_kernel<<<(N_NODES + 255) / 256, 256, 0, stream>>>(x, W_emb, b_emb, W_gcn, h);
    bucket_hist_kernel<<<NBLK_BIN, 256, 0, stream>>>(dst, bcnt);
    bucket_scan_kernel<<<1, 1024, 0, stream>>>(bcnt, boff, bcur);
    bin_edges_kernel<<<NBLK_BIN, 256, 0, stream>>>(src, dst, bcur, binned);
    bucket_csr_kernel<<<NB, 256, 0, stream>>>(boff, binned, sorted_src, off, h, dis);
    aggregate_kernel<<<(N_NODES * 8 + 255) / 256, 256, 0, stream>>>(off, sorted_src,
                                                                    h, dis, agg);
    stats_kernel<<<1024, 256, 0, stream>>>(agg, stats);
    finalize_stats_kernel<<<1, 64, 0, stream>>>(stats, gamma, beta, AB);
    cls_kernel<<<(N_NODES + 255) / 256, 256, 0, stream>>>(agg, AB, W_cls, b_cls, out);
}